// Round 2
// baseline (3924.368 us; speedup 1.0000x reference)
//
#include <hip/hip_runtime.h>
#include <hip/hip_bf16.h>

// Problem constants (from reference setup_inputs)
constexpr int NN   = 50000;   // nodes
constexpr int EE   = 400000;  // edges (before self loops)
constexpr int EP   = 450000;  // edges + self loops
constexpr int D    = 512;     // HEADS*CH
constexpr int F0   = 55;      // input feature dim
constexpr int OUTC = 49;      // classifier out dim

typedef __hip_bfloat16 bf16;

__device__ inline float ldf(const float* p) { return *p; }
__device__ inline float ldf(const bf16* p)  { return __bfloat162float(*p); }
__device__ inline void  stf(float* p, float v) { *p = v; }
__device__ inline void  stf(bf16* p, float v)  { *p = __float2bfloat16(v); }

// ---------------------------------------------------------------------------
// SIMT tiled GEMM: C[M,Nc] = A[M,K] @ B[K,Nc] (+ bias), row-major, fp32 acc.
// BM=BN=64, BK=16, 256 threads, 4x4 acc per thread. A may be fp32 or bf16.
// ---------------------------------------------------------------------------
template <typename TA, typename TC>
__global__ void gemm_t(const TA* __restrict__ A, const float* __restrict__ B,
                       TC* __restrict__ C, const float* __restrict__ bias,
                       int M, int Nc, int K) {
    constexpr int BM = 64, BN = 64, BK = 16;
    __shared__ float As[BK][BM + 1];
    __shared__ float Bs[BK][BN + 1];
    const int tid = threadIdx.x;
    const int tx = tid & 15;        // col group
    const int ty = tid >> 4;        // row group
    const int rowBase = blockIdx.y * BM;
    const int colBase = blockIdx.x * BN;
    float acc[4][4] = {};

    for (int k0 = 0; k0 < K; k0 += BK) {
        #pragma unroll
        for (int i = 0; i < 4; ++i) {
            int idx = tid + i * 256;
            int m = idx >> 4, kk = idx & 15;
            int gr = rowBase + m, gc = k0 + kk;
            float v = 0.f;
            if (gr < M && gc < K) v = ldf(&A[(long)gr * K + gc]);
            As[kk][m] = v;
        }
        #pragma unroll
        for (int i = 0; i < 4; ++i) {
            int idx = tid + i * 256;
            int kk = idx >> 6, n = idx & 63;
            int gr = k0 + kk, gc = colBase + n;
            float v = 0.f;
            if (gr < K && gc < Nc) v = B[(long)gr * Nc + gc];
            Bs[kk][n] = v;
        }
        __syncthreads();
        #pragma unroll
        for (int kk = 0; kk < BK; ++kk) {
            float ra[4], rb[4];
            #pragma unroll
            for (int i = 0; i < 4; ++i) ra[i] = As[kk][ty * 4 + i];
            #pragma unroll
            for (int j = 0; j < 4; ++j) rb[j] = Bs[kk][tx * 4 + j];
            #pragma unroll
            for (int i = 0; i < 4; ++i)
                #pragma unroll
                for (int j = 0; j < 4; ++j)
                    acc[i][j] += ra[i] * rb[j];
        }
        __syncthreads();
    }
    #pragma unroll
    for (int i = 0; i < 4; ++i) {
        int r = rowBase + ty * 4 + i;
        if (r >= M) continue;
        #pragma unroll
        for (int j = 0; j < 4; ++j) {
            int c = colBase + tx * 4 + j;
            if (c >= Nc) continue;
            float v = acc[i][j];
            if (bias) v += bias[c];
            stf(&C[(long)r * Nc + c], v);
        }
    }
}

// ---------------------------------------------------------------------------
// helpers: zero ints (avoid hipMemsetAsync inside graph capture)
// ---------------------------------------------------------------------------
__global__ void zero_ints(int* __restrict__ p, int n) {
    int i = blockIdx.x * blockDim.x + threadIdx.x;
    if (i < n) p[i] = 0;
}

// ---------------------------------------------------------------------------
// CSR build by destination
// ---------------------------------------------------------------------------
__global__ void count_dst(const int* __restrict__ dstIdx, int* __restrict__ cnt) {
    int e = blockIdx.x * blockDim.x + threadIdx.x;
    if (e >= EP) return;
    int dst = (e < EE) ? dstIdx[e] : (e - EE);
    atomicAdd(&cnt[dst], 1);
}

__global__ void scan_offsets(const int* __restrict__ cnt, int* __restrict__ off) {
    // single block, 1024 threads: exclusive scan over NN, off[NN] = total
    __shared__ int sh[1024];
    __shared__ int carry;
    if (threadIdx.x == 0) carry = 0;
    __syncthreads();
    for (int base = 0; base < NN; base += 1024) {
        int i = base + threadIdx.x;
        int v = (i < NN) ? cnt[i] : 0;
        sh[threadIdx.x] = v;
        __syncthreads();
        for (int d = 1; d < 1024; d <<= 1) {
            int t = (threadIdx.x >= d) ? sh[threadIdx.x - d] : 0;
            __syncthreads();
            sh[threadIdx.x] += t;
            __syncthreads();
        }
        int incl = sh[threadIdx.x];
        int total = sh[1023];
        int c = carry;
        if (i < NN) off[i] = c + incl - v;
        __syncthreads();
        if (threadIdx.x == 0) carry = c + total;
        __syncthreads();
    }
    if (threadIdx.x == 0) off[NN] = carry;
}

__global__ void fill_eid(const int* __restrict__ dstIdx, const int* __restrict__ off,
                         int* __restrict__ cnt, int* __restrict__ eid) {
    int e = blockIdx.x * blockDim.x + threadIdx.x;
    if (e >= EP) return;
    int dst = (e < EE) ? dstIdx[e] : (e - EE);
    int pos = off[dst] + atomicAdd(&cnt[dst], 1);
    eid[pos] = e;
}

// ---------------------------------------------------------------------------
// edge logits: one wave (64 lanes x 8 ch) per edge; 4 head dot-products
// XL/XR are bf16 [NN, D]; att fp32 [512]
// ---------------------------------------------------------------------------
__global__ void edge_logits(const bf16* __restrict__ XL, const bf16* __restrict__ XR,
                            const float* __restrict__ att,
                            const int* __restrict__ srcIdx, const int* __restrict__ dstIdx,
                            float* __restrict__ P) {
    int gtid = blockIdx.x * blockDim.x + threadIdx.x;
    int e = gtid >> 6;
    int lane = threadIdx.x & 63;
    if (e >= EP) return;
    int src = (e < EE) ? srcIdx[e] : (e - EE);
    int dst = (e < EE) ? dstIdx[e] : (e - EE);
    union U { uint4 u; __hip_bfloat162 h[4]; };
    U lu, ru;
    lu.u = *(const uint4*)(XL + (long)src * D + lane * 8);
    ru.u = *(const uint4*)(XR + (long)dst * D + lane * 8);
    const float4* a4 = (const float4*)(att + lane * 8);
    float4 a0 = a4[0], a1 = a4[1];
    float af[8] = {a0.x, a0.y, a0.z, a0.w, a1.x, a1.y, a1.z, a1.w};
    float s = 0.f;
    #pragma unroll
    for (int j = 0; j < 4; ++j) {
        float2 l = __bfloat1622float2(lu.h[j]);
        float2 r = __bfloat1622float2(ru.h[j]);
        float v;
        v = l.x + r.x; v = v > 0.f ? v : 0.2f * v; s += v * af[2 * j];
        v = l.y + r.y; v = v > 0.f ? v : 0.2f * v; s += v * af[2 * j + 1];
    }
    // reduce within 16-lane groups (one head per group)
    s += __shfl_xor(s, 1);
    s += __shfl_xor(s, 2);
    s += __shfl_xor(s, 4);
    s += __shfl_xor(s, 8);
    if ((lane & 15) == 0) P[e * 4 + (lane >> 4)] = s;
}

// ---------------------------------------------------------------------------
// per-destination-node fused segment softmax + weighted aggregation + bias + ELU
// one block (256 threads) per node; thread t owns channels t and t+256
// ---------------------------------------------------------------------------
__global__ void node_aggregate(const bf16* __restrict__ XL, const float* __restrict__ P,
                               const int* __restrict__ off, const int* __restrict__ eid,
                               const int* __restrict__ srcIdx,
                               const float* __restrict__ bias, bf16* __restrict__ Hout) {
    int v = blockIdx.x;
    int s0 = off[v], s1 = off[v + 1];
    __shared__ float mh[4], dh[4];
    int tid = threadIdx.x;
    if (tid < 4) {
        float m = -1e30f;
        for (int i = s0; i < s1; ++i) m = fmaxf(m, P[eid[i] * 4 + tid]);
        float den = 0.f;
        for (int i = s0; i < s1; ++i) den += __expf(P[eid[i] * 4 + tid] - m);
        mh[tid] = m;
        dh[tid] = den;
    }
    __syncthreads();
    int c0 = tid, c1 = tid + 256;
    int h0 = c0 >> 7, h1 = c1 >> 7;
    float m0 = mh[h0], r0 = 1.f / dh[h0];
    float m1 = mh[h1], r1 = 1.f / dh[h1];
    float acc0 = 0.f, acc1 = 0.f;
    for (int i = s0; i < s1; ++i) {
        int e = eid[i];
        int src = (e < EE) ? srcIdx[e] : (e - EE);
        float a0 = __expf(P[e * 4 + h0] - m0) * r0;
        float a1 = __expf(P[e * 4 + h1] - m1) * r1;
        const bf16* row = XL + (long)src * D;
        acc0 += a0 * __bfloat162float(row[c0]);
        acc1 += a1 * __bfloat162float(row[c1]);
    }
    float o0 = acc0 + bias[c0];
    float o1 = acc1 + bias[c1];
    // ELU (alpha=1), applied after every GAT layer in the reference
    o0 = o0 > 0.f ? o0 : (__expf(o0) - 1.f);
    o1 = o1 > 0.f ? o1 : (__expf(o1) - 1.f);
    Hout[(long)v * D + c0] = __float2bfloat16(o0);
    Hout[(long)v * D + c1] = __float2bfloat16(o1);
}

// ---------------------------------------------------------------------------
extern "C" void kernel_launch(void* const* d_in, const int* in_sizes, int n_in,
                              void* d_out, int out_size, void* d_ws, size_t ws_size,
                              hipStream_t stream) {
    const float* x    = (const float*)d_in[0];
    const int*   ei   = (const int*)d_in[1];
    const float* W1l  = (const float*)d_in[2];
    const float* W1r  = (const float*)d_in[3];
    const float* att1 = (const float*)d_in[4];
    const float* b1   = (const float*)d_in[5];
    const float* W2l  = (const float*)d_in[6];
    const float* W2r  = (const float*)d_in[7];
    const float* att2 = (const float*)d_in[8];
    const float* b2   = (const float*)d_in[9];
    const float* Wc   = (const float*)d_in[10];
    const float* bc   = (const float*)d_in[11];
    float* out = (float*)d_out;

    const int* srcIdx = ei;
    const int* dstIdx = ei + EE;

    // workspace carve — total ≈ 163 MB
    bf16* XL = (bf16*)d_ws;                   // NN*D bf16
    bf16* XR = XL + (size_t)NN * D;           // NN*D bf16
    bf16* Hb = XR + (size_t)NN * D;           // NN*D bf16
    float* P = (float*)(Hb + (size_t)NN * D); // EP*4 fp32
    int* cnt = (int*)(P + (size_t)EP * 4);    // NN
    int* off = cnt + NN;                      // NN+1
    int* eid = off + (NN + 1);                // EP

    // ---- CSR build (identical every call; ws is re-poisoned so rebuild) ----
    zero_ints<<<(NN + 255) / 256, 256, 0, stream>>>(cnt, NN);
    count_dst<<<(EP + 255) / 256, 256, 0, stream>>>(dstIdx, cnt);
    scan_offsets<<<1, 1024, 0, stream>>>(cnt, off);
    zero_ints<<<(NN + 255) / 256, 256, 0, stream>>>(cnt, NN);
    fill_eid<<<(EP + 255) / 256, 256, 0, stream>>>(dstIdx, off, cnt, eid);

    dim3 gemmGrid((D + 63) / 64, (NN + 63) / 64);
    int elBlocks = (EP * 64 + 255) / 256;

    // ---- layer 1 (fp32 input x, K=55) ----
    gemm_t<float, bf16><<<gemmGrid, 256, 0, stream>>>(x, W1l, XL, nullptr, NN, D, F0);
    gemm_t<float, bf16><<<gemmGrid, 256, 0, stream>>>(x, W1r, XR, nullptr, NN, D, F0);
    edge_logits<<<elBlocks, 256, 0, stream>>>(XL, XR, att1, srcIdx, dstIdx, P);
    node_aggregate<<<NN, 256, 0, stream>>>(XL, P, off, eid, srcIdx, b1, Hb);

    // ---- layers 2 & 3 (bf16 input Hb, K=512; conv2 applied twice) ----
    for (int rep = 0; rep < 2; ++rep) {
        gemm_t<bf16, bf16><<<gemmGrid, 256, 0, stream>>>(Hb, W2l, XL, nullptr, NN, D, D);
        gemm_t<bf16, bf16><<<gemmGrid, 256, 0, stream>>>(Hb, W2r, XR, nullptr, NN, D, D);
        edge_logits<<<elBlocks, 256, 0, stream>>>(XL, XR, att2, srcIdx, dstIdx, P);
        node_aggregate<<<NN, 256, 0, stream>>>(XL, P, off, eid, srcIdx, b2, Hb);
    }

    // ---- classifier ----
    dim3 gridc((OUTC + 63) / 64, (NN + 63) / 64);
    gemm_t<bf16, float><<<gridc, 256, 0, stream>>>(Hb, Wc, out, bc, NN, OUTC, D);
}

// Round 3
// 1857.836 us; speedup vs baseline: 2.1123x; 2.1123x over previous
//
#include <hip/hip_runtime.h>
#include <hip/hip_bf16.h>

// Problem constants (from reference setup_inputs)
constexpr int NN   = 50000;   // nodes
constexpr int EE   = 400000;  // edges (before self loops)
constexpr int EP   = 450000;  // edges + self loops
constexpr int D    = 512;     // HEADS*CH
constexpr int F0   = 55;      // input feature dim
constexpr int OUTC = 49;      // classifier out dim

typedef __hip_bfloat16 bf16;

using frag_ab = __attribute__((ext_vector_type(8))) short;  // 8 bf16 (4 VGPRs)
using frag_cd = __attribute__((ext_vector_type(4))) float;  // 4 fp32

__device__ inline float ldf(const float* p) { return *p; }
__device__ inline float ldf(const bf16* p)  { return __bfloat162float(*p); }
__device__ inline void  stf(float* p, float v) { *p = v; }
__device__ inline void  stf(bf16* p, float v)  { *p = __float2bfloat16(v); }

// ---------------------------------------------------------------------------
// MFMA bf16 GEMM (m97 structure): C[M,N] = A[M,K] @ B[K,N], with B passed
// TRANSPOSED as Bt[N,K]. Row-major everywhere. 128x128 tile, BK=32, 256 thr.
// Requires: N % 128 == 0, K % 32 == 0 (holds: N=512, K=512). M tail clamped.
// ---------------------------------------------------------------------------
__global__ __launch_bounds__(256) void gemm_mfma_bt(
    const bf16* __restrict__ A,   // [M,K]
    const bf16* __restrict__ Bt,  // [N,K]
    bf16* __restrict__ C,         // [M,N]
    int M, int N, int K)
{
    constexpr int BM = 128, BN = 128, BK = 32;
    __shared__ bf16 As[BM * BK];  // row-major, stride BK (64 B/row)
    __shared__ bf16 Bs[BN * BK];

    const int tid  = threadIdx.x;
    const int wave = tid >> 6;
    const int lane = tid & 63;
    const int rowBase = blockIdx.y * BM;
    const int colBase = blockIdx.x * BN;

    frag_cd acc[4][4] = {};

    // --- staging addresses: each wave stages 32 rows of A and 32 rows of Bt
    // via 2 global_load_lds(16B) each; lane i covers row i/4, chunk (i&3)*16B.
    int arow0 = rowBase + wave * 32 + (lane >> 2);
    int arow1 = arow0 + 16;
    if (arow0 >= M) arow0 = M - 1;   // clamp: garbage rows never stored
    if (arow1 >= M) arow1 = M - 1;
    const bf16* gA0 = A + (size_t)arow0 * K + (lane & 3) * 8;
    const bf16* gA1 = A + (size_t)arow1 * K + (lane & 3) * 8;
    const int brow0 = colBase + wave * 32 + (lane >> 2);   // N multiple of 128
    const bf16* gB0 = Bt + (size_t)brow0 * K + (lane & 3) * 8;
    const bf16* gB1 = gB0 + (size_t)16 * K;

    // wave-uniform LDS bases (lane scatter is implicit: base + lane*16B)
    bf16* lA0 = &As[(wave * 32)      * BK];
    bf16* lA1 = &As[(wave * 32 + 16) * BK];
    bf16* lB0 = &Bs[(wave * 32)      * BK];
    bf16* lB1 = &Bs[(wave * 32 + 16) * BK];

    const int m  = lane & 15;   // row (A) / col (B) within 16
    const int kq = lane >> 4;   // k-quad: k offset = kq*8
    const int wm = (wave >> 1) * 64;
    const int wn = (wave & 1) * 64;

    for (int k0 = 0; k0 < K; k0 += BK) {
        __builtin_amdgcn_global_load_lds(
            (const __attribute__((address_space(1))) void*)(gA0 + k0),
            (__attribute__((address_space(3))) void*)lA0, 16, 0, 0);
        __builtin_amdgcn_global_load_lds(
            (const __attribute__((address_space(1))) void*)(gA1 + k0),
            (__attribute__((address_space(3))) void*)lA1, 16, 0, 0);
        __builtin_amdgcn_global_load_lds(
            (const __attribute__((address_space(1))) void*)(gB0 + k0),
            (__attribute__((address_space(3))) void*)lB0, 16, 0, 0);
        __builtin_amdgcn_global_load_lds(
            (const __attribute__((address_space(1))) void*)(gB1 + k0),
            (__attribute__((address_space(3))) void*)lB1, 16, 0, 0);
        __syncthreads();

        frag_ab a[4], b[4];
        #pragma unroll
        for (int i = 0; i < 4; ++i)
            a[i] = *(const frag_ab*)&As[(wm + i * 16 + m) * BK + kq * 8];
        #pragma unroll
        for (int j = 0; j < 4; ++j)
            b[j] = *(const frag_ab*)&Bs[(wn + j * 16 + m) * BK + kq * 8];
        #pragma unroll
        for (int i = 0; i < 4; ++i)
            #pragma unroll
            for (int j = 0; j < 4; ++j)
                acc[i][j] = __builtin_amdgcn_mfma_f32_16x16x32_bf16(
                    a[i], b[j], acc[i][j], 0, 0, 0);
        __syncthreads();
    }

    // epilogue: C/D layout col=lane&15, row=(lane>>4)*4+reg  [m89/m91 verified]
    #pragma unroll
    for (int i = 0; i < 4; ++i) {
        #pragma unroll
        for (int r = 0; r < 4; ++r) {
            int row = rowBase + wm + i * 16 + kq * 4 + r;
            if (row >= M) continue;
            #pragma unroll
            for (int j = 0; j < 4; ++j) {
                int col = colBase + wn + j * 16 + m;
                C[(size_t)row * N + col] = __float2bfloat16(acc[i][j][r]);
            }
        }
    }
}

// ---------------------------------------------------------------------------
// fp32 W[K,N] -> bf16 Wt[N,K] (convert + transpose), 32x32 LDS tile
// ---------------------------------------------------------------------------
__global__ void convert_transpose(const float* __restrict__ W, bf16* __restrict__ Wt,
                                  int K, int N) {
    __shared__ float tile[32][33];
    int bn = blockIdx.x * 32, bk = blockIdx.y * 32;
    int tx = threadIdx.x & 31, ty = threadIdx.x >> 5;  // 32x8
    #pragma unroll
    for (int i = 0; i < 32; i += 8)
        tile[ty + i][tx] = W[(size_t)(bk + ty + i) * N + bn + tx];
    __syncthreads();
    #pragma unroll
    for (int i = 0; i < 32; i += 8)
        Wt[(size_t)(bn + ty + i) * K + bk + tx] = __float2bfloat16(tile[tx][ty + i]);
}

// ---------------------------------------------------------------------------
// SIMT tiled GEMM (kept for K=55 layer-1 and the classifier)
// ---------------------------------------------------------------------------
template <typename TA, typename TC>
__global__ void gemm_t(const TA* __restrict__ A, const float* __restrict__ B,
                       TC* __restrict__ C, const float* __restrict__ bias,
                       int M, int Nc, int K) {
    constexpr int BM = 64, BN = 64, BK = 16;
    __shared__ float As[BK][BM + 1];
    __shared__ float Bs[BK][BN + 1];
    const int tid = threadIdx.x;
    const int tx = tid & 15;
    const int ty = tid >> 4;
    const int rowBase = blockIdx.y * BM;
    const int colBase = blockIdx.x * BN;
    float acc[4][4] = {};

    for (int k0 = 0; k0 < K; k0 += BK) {
        #pragma unroll
        for (int i = 0; i < 4; ++i) {
            int idx = tid + i * 256;
            int mm = idx >> 4, kk = idx & 15;
            int gr = rowBase + mm, gc = k0 + kk;
            float v = 0.f;
            if (gr < M && gc < K) v = ldf(&A[(long)gr * K + gc]);
            As[kk][mm] = v;
        }
        #pragma unroll
        for (int i = 0; i < 4; ++i) {
            int idx = tid + i * 256;
            int kk = idx >> 6, n = idx & 63;
            int gr = k0 + kk, gc = colBase + n;
            float v = 0.f;
            if (gr < K && gc < Nc) v = B[(long)gr * Nc + gc];
            Bs[kk][n] = v;
        }
        __syncthreads();
        #pragma unroll
        for (int kk = 0; kk < BK; ++kk) {
            float ra[4], rb[4];
            #pragma unroll
            for (int i = 0; i < 4; ++i) ra[i] = As[kk][ty * 4 + i];
            #pragma unroll
            for (int j = 0; j < 4; ++j) rb[j] = Bs[kk][tx * 4 + j];
            #pragma unroll
            for (int i = 0; i < 4; ++i)
                #pragma unroll
                for (int j = 0; j < 4; ++j)
                    acc[i][j] += ra[i] * rb[j];
        }
        __syncthreads();
    }
    #pragma unroll
    for (int i = 0; i < 4; ++i) {
        int r = rowBase + ty * 4 + i;
        if (r >= M) continue;
        #pragma unroll
        for (int j = 0; j < 4; ++j) {
            int c = colBase + tx * 4 + j;
            if (c >= Nc) continue;
            float v = acc[i][j];
            if (bias) v += bias[c];
            stf(&C[(long)r * Nc + c], v);
        }
    }
}

// ---------------------------------------------------------------------------
__global__ void zero_ints(int* __restrict__ p, int n) {
    int i = blockIdx.x * blockDim.x + threadIdx.x;
    if (i < n) p[i] = 0;
}

// ---------------------------------------------------------------------------
// CSR build by destination
// ---------------------------------------------------------------------------
__global__ void count_dst(const int* __restrict__ dstIdx, int* __restrict__ cnt) {
    int e = blockIdx.x * blockDim.x + threadIdx.x;
    if (e >= EP) return;
    int dst = (e < EE) ? dstIdx[e] : (e - EE);
    atomicAdd(&cnt[dst], 1);
}

__global__ void scan_offsets(const int* __restrict__ cnt, int* __restrict__ off) {
    __shared__ int sh[1024];
    __shared__ int carry;
    if (threadIdx.x == 0) carry = 0;
    __syncthreads();
    for (int base = 0; base < NN; base += 1024) {
        int i = base + threadIdx.x;
        int v = (i < NN) ? cnt[i] : 0;
        sh[threadIdx.x] = v;
        __syncthreads();
        for (int d = 1; d < 1024; d <<= 1) {
            int t = (threadIdx.x >= d) ? sh[threadIdx.x - d] : 0;
            __syncthreads();
            sh[threadIdx.x] += t;
            __syncthreads();
        }
        int incl = sh[threadIdx.x];
        int total = sh[1023];
        int c = carry;
        if (i < NN) off[i] = c + incl - v;
        __syncthreads();
        if (threadIdx.x == 0) carry = c + total;
        __syncthreads();
    }
    if (threadIdx.x == 0) off[NN] = carry;
}

__global__ void fill_eid(const int* __restrict__ dstIdx, const int* __restrict__ off,
                         int* __restrict__ cnt, int* __restrict__ eid) {
    int e = blockIdx.x * blockDim.x + threadIdx.x;
    if (e >= EP) return;
    int dst = (e < EE) ? dstIdx[e] : (e - EE);
    int pos = off[dst] + atomicAdd(&cnt[dst], 1);
    eid[pos] = e;
}

// ---------------------------------------------------------------------------
// edge logits: one wave (64 lanes x 8 ch) per edge; 4 head dot-products
// ---------------------------------------------------------------------------
__global__ void edge_logits(const bf16* __restrict__ XL, const bf16* __restrict__ XR,
                            const float* __restrict__ att,
                            const int* __restrict__ srcIdx, const int* __restrict__ dstIdx,
                            float* __restrict__ P) {
    int gtid = blockIdx.x * blockDim.x + threadIdx.x;
    int e = gtid >> 6;
    int lane = threadIdx.x & 63;
    if (e >= EP) return;
    int src = (e < EE) ? srcIdx[e] : (e - EE);
    int dst = (e < EE) ? dstIdx[e] : (e - EE);
    union U { uint4 u; __hip_bfloat162 h[4]; };
    U lu, ru;
    lu.u = *(const uint4*)(XL + (long)src * D + lane * 8);
    ru.u = *(const uint4*)(XR + (long)dst * D + lane * 8);
    const float4* a4 = (const float4*)(att + lane * 8);
    float4 a0 = a4[0], a1 = a4[1];
    float af[8] = {a0.x, a0.y, a0.z, a0.w, a1.x, a1.y, a1.z, a1.w};
    float s = 0.f;
    #pragma unroll
    for (int j = 0; j < 4; ++j) {
        float2 l = __bfloat1622float2(lu.h[j]);
        float2 r = __bfloat1622float2(ru.h[j]);
        float v;
        v = l.x + r.x; v = v > 0.f ? v : 0.2f * v; s += v * af[2 * j];
        v = l.y + r.y; v = v > 0.f ? v : 0.2f * v; s += v * af[2 * j + 1];
    }
    s += __shfl_xor(s, 1);
    s += __shfl_xor(s, 2);
    s += __shfl_xor(s, 4);
    s += __shfl_xor(s, 8);
    if ((lane & 15) == 0) P[e * 4 + (lane >> 4)] = s;
}

// ---------------------------------------------------------------------------
// per-destination fused segment softmax + weighted aggregation + bias + ELU
// ---------------------------------------------------------------------------
__global__ void node_aggregate(const bf16* __restrict__ XL, const float* __restrict__ P,
                               const int* __restrict__ off, const int* __restrict__ eid,
                               const int* __restrict__ srcIdx,
                               const float* __restrict__ bias, bf16* __restrict__ Hout) {
    int v = blockIdx.x;
    int s0 = off[v], s1 = off[v + 1];
    __shared__ float mh[4], dh[4];
    int tid = threadIdx.x;
    if (tid < 4) {
        float m = -1e30f;
        for (int i = s0; i < s1; ++i) m = fmaxf(m, P[eid[i] * 4 + tid]);
        float den = 0.f;
        for (int i = s0; i < s1; ++i) den += __expf(P[eid[i] * 4 + tid] - m);
        mh[tid] = m;
        dh[tid] = den;
    }
    __syncthreads();
    int c0 = tid, c1 = tid + 256;
    int h0 = c0 >> 7, h1 = c1 >> 7;
    float m0 = mh[h0], r0 = 1.f / dh[h0];
    float m1 = mh[h1], r1 = 1.f / dh[h1];
    float acc0 = 0.f, acc1 = 0.f;
    for (int i = s0; i < s1; ++i) {
        int e = eid[i];
        int src = (e < EE) ? srcIdx[e] : (e - EE);
        float a0 = __expf(P[e * 4 + h0] - m0) * r0;
        float a1 = __expf(P[e * 4 + h1] - m1) * r1;
        const bf16* row = XL + (long)src * D;
        acc0 += a0 * __bfloat162float(row[c0]);
        acc1 += a1 * __bfloat162float(row[c1]);
    }
    float o0 = acc0 + bias[c0];
    float o1 = acc1 + bias[c1];
    o0 = o0 > 0.f ? o0 : (__expf(o0) - 1.f);
    o1 = o1 > 0.f ? o1 : (__expf(o1) - 1.f);
    Hout[(long)v * D + c0] = __float2bfloat16(o0);
    Hout[(long)v * D + c1] = __float2bfloat16(o1);
}

// ---------------------------------------------------------------------------
extern "C" void kernel_launch(void* const* d_in, const int* in_sizes, int n_in,
                              void* d_out, int out_size, void* d_ws, size_t ws_size,
                              hipStream_t stream) {
    const float* x    = (const float*)d_in[0];
    const int*   ei   = (const int*)d_in[1];
    const float* W1l  = (const float*)d_in[2];
    const float* W1r  = (const float*)d_in[3];
    const float* att1 = (const float*)d_in[4];
    const float* b1   = (const float*)d_in[5];
    const float* W2l  = (const float*)d_in[6];
    const float* W2r  = (const float*)d_in[7];
    const float* att2 = (const float*)d_in[8];
    const float* b2   = (const float*)d_in[9];
    const float* Wc   = (const float*)d_in[10];
    const float* bc   = (const float*)d_in[11];
    float* out = (float*)d_out;

    const int* srcIdx = ei;
    const int* dstIdx = ei + EE;

    // workspace carve — total ≈ 164 MB
    bf16* XL = (bf16*)d_ws;                   // NN*D bf16
    bf16* XR = XL + (size_t)NN * D;           // NN*D bf16
    bf16* Hb = XR + (size_t)NN * D;           // NN*D bf16
    bf16* W2lT = Hb + (size_t)NN * D;         // D*D bf16 (transposed)
    bf16* W2rT = W2lT + (size_t)D * D;        // D*D bf16
    float* P = (float*)(W2rT + (size_t)D * D);// EP*4 fp32
    int* cnt = (int*)(P + (size_t)EP * 4);    // NN
    int* off = cnt + NN;                      // NN+1
    int* eid = off + (NN + 1);                // EP

    // ---- one-time per call: CSR build + weight convert/transpose ----
    zero_ints<<<(NN + 255) / 256, 256, 0, stream>>>(cnt, NN);
    count_dst<<<(EP + 255) / 256, 256, 0, stream>>>(dstIdx, cnt);
    scan_offsets<<<1, 1024, 0, stream>>>(cnt, off);
    zero_ints<<<(NN + 255) / 256, 256, 0, stream>>>(cnt, NN);
    fill_eid<<<(EP + 255) / 256, 256, 0, stream>>>(dstIdx, off, cnt, eid);

    dim3 ctGrid(D / 32, D / 32);
    convert_transpose<<<ctGrid, 256, 0, stream>>>(W2l, W2lT, D, D);
    convert_transpose<<<ctGrid, 256, 0, stream>>>(W2r, W2rT, D, D);

    dim3 gemmGrid((D + 63) / 64, (NN + 63) / 64);
    dim3 mfmaGrid(D / 128, (NN + 127) / 128);
    int elBlocks = (EP * 64 + 255) / 256;

    // ---- layer 1 (fp32 input x, K=55) — SIMT gemm ----
    gemm_t<float, bf16><<<gemmGrid, 256, 0, stream>>>(x, W1l, XL, nullptr, NN, D, F0);
    gemm_t<float, bf16><<<gemmGrid, 256, 0, stream>>>(x, W1r, XR, nullptr, NN, D, F0);
    edge_logits<<<elBlocks, 256, 0, stream>>>(XL, XR, att1, srcIdx, dstIdx, P);
    node_aggregate<<<NN, 256, 0, stream>>>(XL, P, off, eid, srcIdx, b1, Hb);

    // ---- layers 2 & 3 (bf16 Hb, K=512; conv2 applied twice) — MFMA gemm ----
    for (int rep = 0; rep < 2; ++rep) {
        gemm_mfma_bt<<<mfmaGrid, 256, 0, stream>>>(Hb, W2lT, XL, NN, D, D);
        gemm_mfma_bt<<<mfmaGrid, 256, 0, stream>>>(Hb, W2rT, XR, NN, D, D);
        edge_logits<<<elBlocks, 256, 0, stream>>>(XL, XR, att2, srcIdx, dstIdx, P);
        node_aggregate<<<NN, 256, 0, stream>>>(XL, P, off, eid, srcIdx, b2, Hb);
    }

    // ---- classifier ----
    dim3 gridc((OUTC + 63) / 64, (NN + 63) / 64);
    gemm_t<bf16, float><<<gridc, 256, 0, stream>>>(Hb, Wc, out, bc, NN, OUTC, D);
}

// Round 4
// 993.877 us; speedup vs baseline: 3.9485x; 1.8693x over previous
//
#include <hip/hip_runtime.h>
#include <hip/hip_bf16.h>

// Problem constants (from reference setup_inputs)
constexpr int NN   = 50000;   // nodes
constexpr int EE   = 400000;  // edges (before self loops)
constexpr int EP   = 450000;  // edges + self loops
constexpr int D    = 512;     // HEADS*CH
constexpr int F0   = 55;      // input feature dim
constexpr int F0P  = 64;      // padded to MFMA K granularity
constexpr int OUTC = 49;      // classifier out dim

typedef __hip_bfloat16 bf16;

using frag_ab = __attribute__((ext_vector_type(8))) short;  // 8 bf16 (4 VGPRs)
using frag_cd = __attribute__((ext_vector_type(4))) float;  // 4 fp32

__device__ inline void stf(float* p, float v) { *p = v; }
__device__ inline void stf(bf16* p, float v)  { *p = __float2bfloat16(v); }

union BV { uint4 u; __hip_bfloat162 h[4]; };
__device__ inline void unpack8(const BV& b, float* f) {
    #pragma unroll
    for (int j = 0; j < 4; ++j) {
        float2 t = __bfloat1622float2(b.h[j]);
        f[2 * j] = t.x; f[2 * j + 1] = t.y;
    }
}

// ---------------------------------------------------------------------------
// MFMA bf16 GEMM (m97 structure): C[M,*] = A[M,K] @ B, with B passed
// TRANSPOSED as Bt[*,K]. 128x128 tile, BK=32, 256 thr, 4 waves x 4x4 frags.
// Ncs = C row stride AND column bound (cols >= Ncs not stored).
// Grid.x*128 must be <= rows of Bt; K % 32 == 0.
// ---------------------------------------------------------------------------
template <typename TC>
__global__ __launch_bounds__(256) void gemm_mfma_bt(
    const bf16* __restrict__ A,   // [M,K]
    const bf16* __restrict__ Bt,  // [gridx*128, K]
    TC* __restrict__ C,           // [M, Ncs]
    const float* __restrict__ bias,
    int M, int Ncs, int K)
{
    constexpr int BM = 128, BN = 128, BK = 32;
    __shared__ bf16 As[BM * BK];  // row-major, stride BK (64 B/row)
    __shared__ bf16 Bs[BN * BK];

    const int tid  = threadIdx.x;
    const int wave = tid >> 6;
    const int lane = tid & 63;
    const int rowBase = blockIdx.y * BM;
    const int colBase = blockIdx.x * BN;

    frag_cd acc[4][4] = {};

    int arow0 = rowBase + wave * 32 + (lane >> 2);
    int arow1 = arow0 + 16;
    if (arow0 >= M) arow0 = M - 1;   // clamp: garbage rows never stored
    if (arow1 >= M) arow1 = M - 1;
    const bf16* gA0 = A + (size_t)arow0 * K + (lane & 3) * 8;
    const bf16* gA1 = A + (size_t)arow1 * K + (lane & 3) * 8;
    const int brow0 = colBase + wave * 32 + (lane >> 2);
    const bf16* gB0 = Bt + (size_t)brow0 * K + (lane & 3) * 8;
    const bf16* gB1 = gB0 + (size_t)16 * K;

    bf16* lA0 = &As[(wave * 32)      * BK];
    bf16* lA1 = &As[(wave * 32 + 16) * BK];
    bf16* lB0 = &Bs[(wave * 32)      * BK];
    bf16* lB1 = &Bs[(wave * 32 + 16) * BK];

    const int m  = lane & 15;
    const int kq = lane >> 4;
    const int wm = (wave >> 1) * 64;
    const int wn = (wave & 1) * 64;

    for (int k0 = 0; k0 < K; k0 += BK) {
        __builtin_amdgcn_global_load_lds(
            (const __attribute__((address_space(1))) void*)(gA0 + k0),
            (__attribute__((address_space(3))) void*)lA0, 16, 0, 0);
        __builtin_amdgcn_global_load_lds(
            (const __attribute__((address_space(1))) void*)(gA1 + k0),
            (__attribute__((address_space(3))) void*)lA1, 16, 0, 0);
        __builtin_amdgcn_global_load_lds(
            (const __attribute__((address_space(1))) void*)(gB0 + k0),
            (__attribute__((address_space(3))) void*)lB0, 16, 0, 0);
        __builtin_amdgcn_global_load_lds(
            (const __attribute__((address_space(1))) void*)(gB1 + k0),
            (__attribute__((address_space(3))) void*)lB1, 16, 0, 0);
        __syncthreads();

        frag_ab a[4], b[4];
        #pragma unroll
        for (int i = 0; i < 4; ++i)
            a[i] = *(const frag_ab*)&As[(wm + i * 16 + m) * BK + kq * 8];
        #pragma unroll
        for (int j = 0; j < 4; ++j)
            b[j] = *(const frag_ab*)&Bs[(wn + j * 16 + m) * BK + kq * 8];
        #pragma unroll
        for (int i = 0; i < 4; ++i)
            #pragma unroll
            for (int j = 0; j < 4; ++j)
                acc[i][j] = __builtin_amdgcn_mfma_f32_16x16x32_bf16(
                    a[i], b[j], acc[i][j], 0, 0, 0);
        __syncthreads();
    }

    // epilogue: C/D layout col=lane&15, row=(lane>>4)*4+reg  [m89/m91 verified]
    #pragma unroll
    for (int i = 0; i < 4; ++i) {
        #pragma unroll
        for (int r = 0; r < 4; ++r) {
            int row = rowBase + wm + i * 16 + kq * 4 + r;
            if (row >= M) continue;
            #pragma unroll
            for (int j = 0; j < 4; ++j) {
                int col = colBase + wn + j * 16 + m;
                if (col >= Ncs) continue;
                float v = acc[i][j][r];
                if (bias) v += bias[col];
                stf(&C[(size_t)row * Ncs + col], v);
            }
        }
    }
}

// ---------------------------------------------------------------------------
// weight prep kernels
// ---------------------------------------------------------------------------
// fp32 W[K,N] -> bf16 Wt[N,K], 32x32 LDS tile (for 512x512 weights)
__global__ void convert_transpose(const float* __restrict__ W, bf16* __restrict__ Wt,
                                  int K, int N) {
    __shared__ float tile[32][33];
    int bn = blockIdx.x * 32, bk = blockIdx.y * 32;
    int tx = threadIdx.x & 31, ty = threadIdx.x >> 5;  // 32x8
    #pragma unroll
    for (int i = 0; i < 32; i += 8)
        tile[ty + i][tx] = W[(size_t)(bk + ty + i) * N + bn + tx];
    __syncthreads();
    #pragma unroll
    for (int i = 0; i < 32; i += 8)
        Wt[(size_t)(bn + ty + i) * K + bk + tx] = __float2bfloat16(tile[tx][ty + i]);
}

// x[NN,55] fp32 -> Xpad[NN,64] bf16 (zero pad)
__global__ void pad_convert_x(const float* __restrict__ x, bf16* __restrict__ Xp) {
    int idx = blockIdx.x * blockDim.x + threadIdx.x;
    if (idx >= NN * F0P) return;
    int n = idx >> 6, t = idx & 63;
    float v = (t < F0) ? x[n * F0 + t] : 0.f;
    Xp[idx] = __float2bfloat16(v);
}

// W1[55,512] fp32 -> W1t[512,64] bf16 (zero pad K)
__global__ void conv_transpose_w1(const float* __restrict__ W, bf16* __restrict__ Wt) {
    int n = blockIdx.x;           // 512
    int k = threadIdx.x;          // 64
    float v = (k < F0) ? W[(size_t)k * D + n] : 0.f;
    Wt[n * F0P + k] = __float2bfloat16(v);
}

// Wc[512,49] fp32 -> WcT[128,512] bf16 (rows >= 49 zero)
__global__ void conv_transpose_wc(const float* __restrict__ W, bf16* __restrict__ Wt) {
    int n = blockIdx.x;           // 128
    for (int k = threadIdx.x; k < D; k += blockDim.x) {
        float v = (n < OUTC) ? W[(size_t)k * OUTC + n] : 0.f;
        Wt[(size_t)n * D + k] = __float2bfloat16(v);
    }
}

// ---------------------------------------------------------------------------
__global__ void zero_ints(int* __restrict__ p, int n) {
    int i = blockIdx.x * blockDim.x + threadIdx.x;
    if (i < n) p[i] = 0;
}

// ---------------------------------------------------------------------------
// CSR build by destination; srcPos[pos] = source node of CSR slot pos
// ---------------------------------------------------------------------------
__global__ void count_dst(const int* __restrict__ dstIdx, int* __restrict__ cnt) {
    int e = blockIdx.x * blockDim.x + threadIdx.x;
    if (e >= EP) return;
    int dst = (e < EE) ? dstIdx[e] : (e - EE);
    atomicAdd(&cnt[dst], 1);
}

__global__ void scan_offsets(const int* __restrict__ cnt, int* __restrict__ off) {
    __shared__ int sh[1024];
    __shared__ int carry;
    if (threadIdx.x == 0) carry = 0;
    __syncthreads();
    for (int base = 0; base < NN; base += 1024) {
        int i = base + threadIdx.x;
        int v = (i < NN) ? cnt[i] : 0;
        sh[threadIdx.x] = v;
        __syncthreads();
        for (int d = 1; d < 1024; d <<= 1) {
            int t = (threadIdx.x >= d) ? sh[threadIdx.x - d] : 0;
            __syncthreads();
            sh[threadIdx.x] += t;
            __syncthreads();
        }
        int incl = sh[threadIdx.x];
        int total = sh[1023];
        int c = carry;
        if (i < NN) off[i] = c + incl - v;
        __syncthreads();
        if (threadIdx.x == 0) carry = c + total;
        __syncthreads();
    }
    if (threadIdx.x == 0) off[NN] = carry;
}

__global__ void fill_srcpos(const int* __restrict__ srcIdx, const int* __restrict__ dstIdx,
                            const int* __restrict__ off, int* __restrict__ cnt,
                            int* __restrict__ srcPos) {
    int e = blockIdx.x * blockDim.x + threadIdx.x;
    if (e >= EP) return;
    int dst = (e < EE) ? dstIdx[e] : (e - EE);
    int src = (e < EE) ? srcIdx[e] : (e - EE);
    int pos = off[dst] + atomicAdd(&cnt[dst], 1);
    srcPos[pos] = src;
}

// ---------------------------------------------------------------------------
// fused edge logits + online segment softmax. One wave per destination node.
// Lane l owns channels [l*8, l*8+8); head h = l>>4. XR[v] held in registers.
// Writes: P[pos*4+h] = logit; M4/R4[v*4+h] = running max / 1/denom.
// ---------------------------------------------------------------------------
__global__ __launch_bounds__(256) void edge_logits_softmax(
    const bf16* __restrict__ XL, const bf16* __restrict__ XR,
    const float* __restrict__ att,
    const int* __restrict__ off, const int* __restrict__ srcPos,
    float* __restrict__ P, float* __restrict__ M4, float* __restrict__ R4)
{
    int v = blockIdx.x * 4 + (threadIdx.x >> 6);
    if (v >= NN) return;
    int lane = threadIdx.x & 63;
    int h = lane >> 4;

    BV rb; rb.u = *(const uint4*)(XR + (size_t)v * D + lane * 8);
    float xr[8]; unpack8(rb, xr);
    const float4* a4 = (const float4*)(att + lane * 8);
    float4 aa = a4[0], ab = a4[1];
    float at[8] = {aa.x, aa.y, aa.z, aa.w, ab.x, ab.y, ab.z, ab.w};

    int s0 = off[v], s1 = off[v + 1];
    float m = -1e30f, d = 0.f;
    for (int i = s0; i < s1; ++i) {
        int src = srcPos[i];
        BV lb; lb.u = *(const uint4*)(XL + (size_t)src * D + lane * 8);
        float xl[8]; unpack8(lb, xl);
        float s = 0.f;
        #pragma unroll
        for (int j = 0; j < 8; ++j) {
            float t = xl[j] + xr[j];
            t = t > 0.f ? t : 0.2f * t;
            s += t * at[j];
        }
        s += __shfl_xor(s, 1);
        s += __shfl_xor(s, 2);
        s += __shfl_xor(s, 4);
        s += __shfl_xor(s, 8);
        if ((lane & 15) == 0) P[(size_t)i * 4 + h] = s;
        float mn = fmaxf(m, s);
        d = d * __expf(m - mn) + __expf(s - mn);
        m = mn;
    }
    if ((lane & 15) == 0) {
        M4[v * 4 + h] = m;
        R4[v * 4 + h] = 1.f / d;
    }
}

// ---------------------------------------------------------------------------
// weighted aggregation + bias + ELU. One wave per destination node.
// Lane l owns channels [l*8, l*8+8); alpha recomputed from stored (m, r).
// ---------------------------------------------------------------------------
__global__ __launch_bounds__(256) void node_aggregate(
    const bf16* __restrict__ XL, const float* __restrict__ P,
    const float* __restrict__ M4, const float* __restrict__ R4,
    const int* __restrict__ off, const int* __restrict__ srcPos,
    const float* __restrict__ bias, bf16* __restrict__ Hout)
{
    int v = blockIdx.x * 4 + (threadIdx.x >> 6);
    if (v >= NN) return;
    int lane = threadIdx.x & 63;
    int h = lane >> 4;

    float m = M4[v * 4 + h];
    float r = R4[v * 4 + h];
    int s0 = off[v], s1 = off[v + 1];

    float acc[8] = {};
    for (int i = s0; i < s1; ++i) {
        int src = srcPos[i];
        float a = __expf(P[(size_t)i * 4 + h] - m) * r;
        BV lb; lb.u = *(const uint4*)(XL + (size_t)src * D + lane * 8);
        float xl[8]; unpack8(lb, xl);
        #pragma unroll
        for (int j = 0; j < 8; ++j) acc[j] += a * xl[j];
    }

    const float4* b4 = (const float4*)(bias + lane * 8);
    float4 ba = b4[0], bb = b4[1];
    float bi[8] = {ba.x, ba.y, ba.z, ba.w, bb.x, bb.y, bb.z, bb.w};
    BV ob;
    #pragma unroll
    for (int j = 0; j < 4; ++j) {
        float o0 = acc[2 * j] + bi[2 * j];
        float o1 = acc[2 * j + 1] + bi[2 * j + 1];
        o0 = o0 > 0.f ? o0 : (__expf(o0) - 1.f);   // ELU
        o1 = o1 > 0.f ? o1 : (__expf(o1) - 1.f);
        ob.h[j] = __hip_bfloat162{__float2bfloat16(o0), __float2bfloat16(o1)};
    }
    *(uint4*)(Hout + (size_t)v * D + lane * 8) = ob.u;
}

// ---------------------------------------------------------------------------
extern "C" void kernel_launch(void* const* d_in, const int* in_sizes, int n_in,
                              void* d_out, int out_size, void* d_ws, size_t ws_size,
                              hipStream_t stream) {
    const float* x    = (const float*)d_in[0];
    const int*   ei   = (const int*)d_in[1];
    const float* W1l  = (const float*)d_in[2];
    const float* W1r  = (const float*)d_in[3];
    const float* att1 = (const float*)d_in[4];
    const float* b1   = (const float*)d_in[5];
    const float* W2l  = (const float*)d_in[6];
    const float* W2r  = (const float*)d_in[7];
    const float* att2 = (const float*)d_in[8];
    const float* b2   = (const float*)d_in[9];
    const float* Wc   = (const float*)d_in[10];
    const float* bc   = (const float*)d_in[11];
    float* out = (float*)d_out;

    const int* srcIdx = ei;
    const int* dstIdx = ei + EE;

    // workspace carve — total ≈ 172 MB
    bf16* XL   = (bf16*)d_ws;                    // NN*D
    bf16* XR   = XL + (size_t)NN * D;            // NN*D
    bf16* Hb   = XR + (size_t)NN * D;            // NN*D
    bf16* Xpad = Hb + (size_t)NN * D;            // NN*F0P
    bf16* W2lT = Xpad + (size_t)NN * F0P;        // D*D
    bf16* W2rT = W2lT + (size_t)D * D;           // D*D
    bf16* W1lT = W2rT + (size_t)D * D;           // D*F0P
    bf16* W1rT = W1lT + (size_t)D * F0P;         // D*F0P
    bf16* WcT  = W1rT + (size_t)D * F0P;         // 128*D
    float* P   = (float*)(WcT + (size_t)128 * D);// EP*4
    float* M4  = P + (size_t)EP * 4;             // NN*4
    float* R4  = M4 + (size_t)NN * 4;            // NN*4
    int* cnt   = (int*)(R4 + (size_t)NN * 4);    // NN
    int* off   = cnt + NN;                       // NN+1
    int* srcPos= off + (NN + 1);                 // EP

    // ---- one-time per call: CSR build + weight prep ----
    zero_ints<<<(NN + 255) / 256, 256, 0, stream>>>(cnt, NN);
    count_dst<<<(EP + 255) / 256, 256, 0, stream>>>(dstIdx, cnt);
    scan_offsets<<<1, 1024, 0, stream>>>(cnt, off);
    zero_ints<<<(NN + 255) / 256, 256, 0, stream>>>(cnt, NN);
    fill_srcpos<<<(EP + 255) / 256, 256, 0, stream>>>(srcIdx, dstIdx, off, cnt, srcPos);

    dim3 ctGrid(D / 32, D / 32);
    convert_transpose<<<ctGrid, 256, 0, stream>>>(W2l, W2lT, D, D);
    convert_transpose<<<ctGrid, 256, 0, stream>>>(W2r, W2rT, D, D);
    conv_transpose_w1<<<D, F0P, 0, stream>>>(W1l, W1lT);
    conv_transpose_w1<<<D, F0P, 0, stream>>>(W1r, W1rT);
    conv_transpose_wc<<<128, 256, 0, stream>>>(Wc, WcT);
    pad_convert_x<<<(NN * F0P + 255) / 256, 256, 0, stream>>>(x, Xpad);

    dim3 mfmaGrid(D / 128, (NN + 127) / 128);
    int nodeBlocks = (NN + 3) / 4;

    // ---- layer 1 (Xpad bf16, K=64) ----
    gemm_mfma_bt<bf16><<<mfmaGrid, 256, 0, stream>>>(Xpad, W1lT, XL, nullptr, NN, D, F0P);
    gemm_mfma_bt<bf16><<<mfmaGrid, 256, 0, stream>>>(Xpad, W1rT, XR, nullptr, NN, D, F0P);
    edge_logits_softmax<<<nodeBlocks, 256, 0, stream>>>(XL, XR, att1, off, srcPos, P, M4, R4);
    node_aggregate<<<nodeBlocks, 256, 0, stream>>>(XL, P, M4, R4, off, srcPos, b1, Hb);

    // ---- layers 2 & 3 (bf16 Hb, K=512; conv2 applied twice) ----
    for (int rep = 0; rep < 2; ++rep) {
        gemm_mfma_bt<bf16><<<mfmaGrid, 256, 0, stream>>>(Hb, W2lT, XL, nullptr, NN, D, D);
        gemm_mfma_bt<bf16><<<mfmaGrid, 256, 0, stream>>>(Hb, W2rT, XR, nullptr, NN, D, D);
        edge_logits_softmax<<<nodeBlocks, 256, 0, stream>>>(XL, XR, att2, off, srcPos, P, M4, R4);
        node_aggregate<<<nodeBlocks, 256, 0, stream>>>(XL, P, M4, R4, off, srcPos, b2, Hb);
    }

    // ---- classifier: C[NN,49] fp32 = Hb @ Wc + bc (N padded to 128) ----
    dim3 gridc(1, (NN + 127) / 128);
    gemm_mfma_bt<float><<<gridc, 256, 0, stream>>>(Hb, WcT, out, bc, NN, OUTC, D);
}

// Round 5
// 659.385 us; speedup vs baseline: 5.9516x; 1.5073x over previous
//
#include <hip/hip_runtime.h>
#include <hip/hip_bf16.h>

// Problem constants (from reference setup_inputs)
constexpr int NN   = 50000;   // nodes
constexpr int EE   = 400000;  // edges (before self loops)
constexpr int EP   = 450000;  // edges + self loops
constexpr int D    = 512;     // HEADS*CH
constexpr int D2   = 1024;    // XL||XR fused row stride
constexpr int F0   = 55;      // input feature dim
constexpr int F0P  = 64;      // padded to MFMA K granularity
constexpr int OUTC = 49;      // classifier out dim

typedef __hip_bfloat16 bf16;

using frag_ab = __attribute__((ext_vector_type(8))) short;  // 8 bf16 (4 VGPRs)
using frag_cd = __attribute__((ext_vector_type(4))) float;  // 4 fp32

__device__ inline void stf(float* p, float v) { *p = v; }
__device__ inline void stf(bf16* p, float v)  { *p = __float2bfloat16(v); }

union BV { uint4 u; __hip_bfloat162 h[4]; };
__device__ inline void unpack8(const BV& b, float* f) {
    #pragma unroll
    for (int j = 0; j < 4; ++j) {
        float2 t = __bfloat1622float2(b.h[j]);
        f[2 * j] = t.x; f[2 * j + 1] = t.y;
    }
}

// ---------------------------------------------------------------------------
// MFMA bf16 GEMM (m97 structure): C[M,*] = A[M,K] @ B, with B passed
// TRANSPOSED as Bt[*,K]. 128x128 tile, BK=32, 256 thr, 4 waves x 4x4 frags.
// Ncs = C row stride AND column bound (cols >= Ncs not stored).
// Grid.x*128 must be <= rows of Bt; K % 32 == 0.
// ---------------------------------------------------------------------------
template <typename TC>
__global__ __launch_bounds__(256) void gemm_mfma_bt(
    const bf16* __restrict__ A,   // [M,K]
    const bf16* __restrict__ Bt,  // [gridx*128, K]
    TC* __restrict__ C,           // [M, Ncs]
    const float* __restrict__ bias,
    int M, int Ncs, int K)
{
    constexpr int BM = 128, BN = 128, BK = 32;
    __shared__ bf16 As[BM * BK];  // row-major, stride BK (64 B/row)
    __shared__ bf16 Bs[BN * BK];

    const int tid  = threadIdx.x;
    const int wave = tid >> 6;
    const int lane = tid & 63;
    const int rowBase = blockIdx.y * BM;
    const int colBase = blockIdx.x * BN;

    frag_cd acc[4][4] = {};

    int arow0 = rowBase + wave * 32 + (lane >> 2);
    int arow1 = arow0 + 16;
    if (arow0 >= M) arow0 = M - 1;   // clamp: garbage rows never stored
    if (arow1 >= M) arow1 = M - 1;
    const bf16* gA0 = A + (size_t)arow0 * K + (lane & 3) * 8;
    const bf16* gA1 = A + (size_t)arow1 * K + (lane & 3) * 8;
    const int brow0 = colBase + wave * 32 + (lane >> 2);
    const bf16* gB0 = Bt + (size_t)brow0 * K + (lane & 3) * 8;
    const bf16* gB1 = gB0 + (size_t)16 * K;

    bf16* lA0 = &As[(wave * 32)      * BK];
    bf16* lA1 = &As[(wave * 32 + 16) * BK];
    bf16* lB0 = &Bs[(wave * 32)      * BK];
    bf16* lB1 = &Bs[(wave * 32 + 16) * BK];

    const int m  = lane & 15;
    const int kq = lane >> 4;
    const int wm = (wave >> 1) * 64;
    const int wn = (wave & 1) * 64;

    for (int k0 = 0; k0 < K; k0 += BK) {
        __builtin_amdgcn_global_load_lds(
            (const __attribute__((address_space(1))) void*)(gA0 + k0),
            (__attribute__((address_space(3))) void*)lA0, 16, 0, 0);
        __builtin_amdgcn_global_load_lds(
            (const __attribute__((address_space(1))) void*)(gA1 + k0),
            (__attribute__((address_space(3))) void*)lA1, 16, 0, 0);
        __builtin_amdgcn_global_load_lds(
            (const __attribute__((address_space(1))) void*)(gB0 + k0),
            (__attribute__((address_space(3))) void*)lB0, 16, 0, 0);
        __builtin_amdgcn_global_load_lds(
            (const __attribute__((address_space(1))) void*)(gB1 + k0),
            (__attribute__((address_space(3))) void*)lB1, 16, 0, 0);
        __syncthreads();

        frag_ab a[4], b[4];
        #pragma unroll
        for (int i = 0; i < 4; ++i)
            a[i] = *(const frag_ab*)&As[(wm + i * 16 + m) * BK + kq * 8];
        #pragma unroll
        for (int j = 0; j < 4; ++j)
            b[j] = *(const frag_ab*)&Bs[(wn + j * 16 + m) * BK + kq * 8];
        #pragma unroll
        for (int i = 0; i < 4; ++i)
            #pragma unroll
            for (int j = 0; j < 4; ++j)
                acc[i][j] = __builtin_amdgcn_mfma_f32_16x16x32_bf16(
                    a[i], b[j], acc[i][j], 0, 0, 0);
        __syncthreads();
    }

    // epilogue: C/D layout col=lane&15, row=(lane>>4)*4+reg  [m89/m91 verified]
    #pragma unroll
    for (int i = 0; i < 4; ++i) {
        #pragma unroll
        for (int r = 0; r < 4; ++r) {
            int row = rowBase + wm + i * 16 + kq * 4 + r;
            if (row >= M) continue;
            #pragma unroll
            for (int j = 0; j < 4; ++j) {
                int col = colBase + wn + j * 16 + m;
                if (col >= Ncs) continue;
                float v = acc[i][j][r];
                if (bias) v += bias[col];
                stf(&C[(size_t)row * Ncs + col], v);
            }
        }
    }
}

// ---------------------------------------------------------------------------
// weight prep kernels
// ---------------------------------------------------------------------------
// fp32 W[K,N] -> bf16 Wt[N,K], 32x32 LDS tile (for 512x512 weights)
__global__ void convert_transpose(const float* __restrict__ W, bf16* __restrict__ Wt,
                                  int K, int N) {
    __shared__ float tile[32][33];
    int bn = blockIdx.x * 32, bk = blockIdx.y * 32;
    int tx = threadIdx.x & 31, ty = threadIdx.x >> 5;  // 32x8
    #pragma unroll
    for (int i = 0; i < 32; i += 8)
        tile[ty + i][tx] = W[(size_t)(bk + ty + i) * N + bn + tx];
    __syncthreads();
    #pragma unroll
    for (int i = 0; i < 32; i += 8)
        Wt[(size_t)(bn + ty + i) * K + bk + tx] = __float2bfloat16(tile[tx][ty + i]);
}

// x[NN,55] fp32 -> Xpad[NN,64] bf16 (zero pad)
__global__ void pad_convert_x(const float* __restrict__ x, bf16* __restrict__ Xp) {
    int idx = blockIdx.x * blockDim.x + threadIdx.x;
    if (idx >= NN * F0P) return;
    int n = idx >> 6, t = idx & 63;
    float v = (t < F0) ? x[n * F0 + t] : 0.f;
    Xp[idx] = __float2bfloat16(v);
}

// W1[55,512] fp32 -> W1t[512,64] bf16 (zero pad K)
__global__ void conv_transpose_w1(const float* __restrict__ W, bf16* __restrict__ Wt) {
    int n = blockIdx.x;           // 512
    int k = threadIdx.x;          // 64
    float v = (k < F0) ? W[(size_t)k * D + n] : 0.f;
    Wt[n * F0P + k] = __float2bfloat16(v);
}

// Wc[512,49] fp32 -> WcT[128,512] bf16 (rows >= 49 zero)
__global__ void conv_transpose_wc(const float* __restrict__ W, bf16* __restrict__ Wt) {
    int n = blockIdx.x;           // 128
    for (int k = threadIdx.x; k < D; k += blockDim.x) {
        float v = (n < OUTC) ? W[(size_t)k * OUTC + n] : 0.f;
        Wt[(size_t)n * D + k] = __float2bfloat16(v);
    }
}

// ---------------------------------------------------------------------------
__global__ void zero_ints(int* __restrict__ p, int n) {
    int i = blockIdx.x * blockDim.x + threadIdx.x;
    if (i < n) p[i] = 0;
}

// ---------------------------------------------------------------------------
// CSR build by destination; srcPos[pos] = source node of CSR slot pos
// ---------------------------------------------------------------------------
__global__ void count_dst(const int* __restrict__ dstIdx, int* __restrict__ cnt) {
    int e = blockIdx.x * blockDim.x + threadIdx.x;
    if (e >= EP) return;
    int dst = (e < EE) ? dstIdx[e] : (e - EE);
    atomicAdd(&cnt[dst], 1);
}

// --- 3-phase parallel exclusive scan over cnt[NN] -> off[NN+1] -------------
__global__ void scan_blocks(const int* __restrict__ cnt, int* __restrict__ off,
                            int* __restrict__ bsum) {
    __shared__ int sh[1024];
    int i = blockIdx.x * 1024 + threadIdx.x;
    int v = (i < NN) ? cnt[i] : 0;
    sh[threadIdx.x] = v;
    __syncthreads();
    #pragma unroll
    for (int d = 1; d < 1024; d <<= 1) {
        int t = (threadIdx.x >= d) ? sh[threadIdx.x - d] : 0;
        __syncthreads();
        sh[threadIdx.x] += t;
        __syncthreads();
    }
    if (i < NN) off[i] = sh[threadIdx.x] - v;   // local exclusive
    if (threadIdx.x == 1023) bsum[blockIdx.x] = sh[1023];
}

__global__ void scan_bsums(int* __restrict__ bsum, int* __restrict__ bbase,
                           int* __restrict__ off, int nb) {
    int lane = threadIdx.x;  // single wave of 64
    int orig = (lane < nb) ? bsum[lane] : 0;
    int v = orig;
    #pragma unroll
    for (int d = 1; d < 64; d <<= 1) {
        int t = __shfl_up(v, d);
        if (lane >= d) v += t;
    }
    if (lane < nb) bbase[lane] = v - orig;      // exclusive base per block
    if (lane == 63) off[NN] = v;                // grand total
}

__global__ void add_base(int* __restrict__ off, const int* __restrict__ bbase) {
    int i = blockIdx.x * 1024 + threadIdx.x;
    if (blockIdx.x == 0 || i >= NN) return;
    off[i] += bbase[blockIdx.x];
}

__global__ void fill_srcpos(const int* __restrict__ srcIdx, const int* __restrict__ dstIdx,
                            const int* __restrict__ off, int* __restrict__ cnt,
                            int* __restrict__ srcPos) {
    int e = blockIdx.x * blockDim.x + threadIdx.x;
    if (e >= EP) return;
    int dst = (e < EE) ? dstIdx[e] : (e - EE);
    int src = (e < EE) ? srcIdx[e] : (e - EE);
    int pos = off[dst] + atomicAdd(&cnt[dst], 1);
    srcPos[pos] = src;
}

// ---------------------------------------------------------------------------
// FUSED per-node GATv2 edge phase (flash-style online softmax + aggregate).
// One wave per destination node. Lane l owns channels [l*8, l*8+8); head = l>>4.
// XLR row layout: [XL(512) | XR(512)], stride D2. Output Hb[NN,D] + bias + ELU.
// Each edge's XL row (1 KB) is gathered exactly ONCE.
// ---------------------------------------------------------------------------
__global__ __launch_bounds__(256) void gat_edge_fused(
    const bf16* __restrict__ XLR, const float* __restrict__ att,
    const int* __restrict__ off, const int* __restrict__ srcPos,
    const float* __restrict__ bias, bf16* __restrict__ Hout)
{
    int v = blockIdx.x * 4 + (threadIdx.x >> 6);
    if (v >= NN) return;
    int lane = threadIdx.x & 63;

    BV rb; rb.u = *(const uint4*)(XLR + (size_t)v * D2 + D + lane * 8);
    float xr[8]; unpack8(rb, xr);
    const float4* a4 = (const float4*)(att + lane * 8);
    float4 aa = a4[0], ab = a4[1];
    float at[8] = {aa.x, aa.y, aa.z, aa.w, ab.x, ab.y, ab.z, ab.w};

    int s0 = off[v], s1 = off[v + 1];
    float m = -1e30f, den = 0.f;
    float acc[8] = {};
    for (int i = s0; i < s1; ++i) {
        int src = srcPos[i];
        BV lb; lb.u = *(const uint4*)(XLR + (size_t)src * D2 + lane * 8);
        float xl[8]; unpack8(lb, xl);
        float s = 0.f;
        #pragma unroll
        for (int j = 0; j < 8; ++j) {
            float t = xl[j] + xr[j];
            t = t > 0.f ? t : 0.2f * t;    // LeakyReLU(0.2)
            s += t * at[j];
        }
        s += __shfl_xor(s, 1);
        s += __shfl_xor(s, 2);
        s += __shfl_xor(s, 4);
        s += __shfl_xor(s, 8);             // all 16 lanes of head hold logit
        float mn = fmaxf(m, s);
        float scale = __expf(m - mn);      // first iter: exp(-inf) = 0
        float p = __expf(s - mn);
        den = den * scale + p;
        #pragma unroll
        for (int j = 0; j < 8; ++j) acc[j] = acc[j] * scale + p * xl[j];
        m = mn;
    }
    float r = 1.f / den;

    const float4* b4 = (const float4*)(bias + lane * 8);
    float4 ba = b4[0], bb = b4[1];
    float bi[8] = {ba.x, ba.y, ba.z, ba.w, bb.x, bb.y, bb.z, bb.w};
    BV ob;
    #pragma unroll
    for (int j = 0; j < 4; ++j) {
        float o0 = acc[2 * j] * r + bi[2 * j];
        float o1 = acc[2 * j + 1] * r + bi[2 * j + 1];
        o0 = o0 > 0.f ? o0 : (__expf(o0) - 1.f);   // ELU
        o1 = o1 > 0.f ? o1 : (__expf(o1) - 1.f);
        ob.h[j] = __hip_bfloat162{__float2bfloat16(o0), __float2bfloat16(o1)};
    }
    *(uint4*)(Hout + (size_t)v * D + lane * 8) = ob.u;
}

// ---------------------------------------------------------------------------
extern "C" void kernel_launch(void* const* d_in, const int* in_sizes, int n_in,
                              void* d_out, int out_size, void* d_ws, size_t ws_size,
                              hipStream_t stream) {
    const float* x    = (const float*)d_in[0];
    const int*   ei   = (const int*)d_in[1];
    const float* W1l  = (const float*)d_in[2];
    const float* W1r  = (const float*)d_in[3];
    const float* att1 = (const float*)d_in[4];
    const float* b1   = (const float*)d_in[5];
    const float* W2l  = (const float*)d_in[6];
    const float* W2r  = (const float*)d_in[7];
    const float* att2 = (const float*)d_in[8];
    const float* b2   = (const float*)d_in[9];
    const float* Wc   = (const float*)d_in[10];
    const float* bc   = (const float*)d_in[11];
    float* out = (float*)d_out;

    const int* srcIdx = ei;
    const int* dstIdx = ei + EE;

    constexpr int NB = (NN + 1023) / 1024;   // 49 scan blocks

    // workspace carve — total ≈ 166 MB
    bf16* XLR  = (bf16*)d_ws;                    // NN*D2   (XL || XR)
    bf16* Hb   = XLR + (size_t)NN * D2;          // NN*D
    bf16* Xpad = Hb + (size_t)NN * D;            // NN*F0P
    bf16* W2T  = Xpad + (size_t)NN * F0P;        // 1024*D   (W2lT || W2rT rows)
    bf16* W1T  = W2T + (size_t)D2 * D;           // 1024*F0P
    bf16* WcT  = W1T + (size_t)D2 * F0P;         // 128*D
    int* cnt   = (int*)(WcT + (size_t)128 * D);  // NN
    int* cnt2  = cnt + NN;                       // NN
    int* off   = cnt2 + NN;                      // NN+1
    int* srcPos= off + (NN + 1);                 // EP
    int* bsum  = srcPos + EP;                    // NB
    int* bbase = bsum + NB;                      // NB

    // ---- one-time per call: CSR build + weight prep ----
    zero_ints<<<(2 * NN + 255) / 256, 256, 0, stream>>>(cnt, 2 * NN);
    count_dst<<<(EP + 255) / 256, 256, 0, stream>>>(dstIdx, cnt);
    scan_blocks<<<NB, 1024, 0, stream>>>(cnt, off, bsum);
    scan_bsums<<<1, 64, 0, stream>>>(bsum, bbase, off, NB);
    add_base<<<NB, 1024, 0, stream>>>(off, bbase);
    fill_srcpos<<<(EP + 255) / 256, 256, 0, stream>>>(srcIdx, dstIdx, off, cnt2, srcPos);

    dim3 ctGrid(D / 32, D / 32);
    convert_transpose<<<ctGrid, 256, 0, stream>>>(W2l, W2T, D, D);                 // rows 0..511
    convert_transpose<<<ctGrid, 256, 0, stream>>>(W2r, W2T + (size_t)D * D, D, D); // rows 512..1023
    conv_transpose_w1<<<D, F0P, 0, stream>>>(W1l, W1T);
    conv_transpose_w1<<<D, F0P, 0, stream>>>(W1r, W1T + (size_t)D * F0P);
    conv_transpose_wc<<<128, 256, 0, stream>>>(Wc, WcT);
    pad_convert_x<<<(NN * F0P + 255) / 256, 256, 0, stream>>>(x, Xpad);

    dim3 gemmGrid(D2 / 128, (NN + 127) / 128);   // fused L+R: N=1024
    int nodeBlocks = (NN + 3) / 4;

    // ---- layer 1 (Xpad bf16, K=64): one GEMM produces XL||XR ----
    gemm_mfma_bt<bf16><<<gemmGrid, 256, 0, stream>>>(Xpad, W1T, XLR, nullptr, NN, D2, F0P);
    gat_edge_fused<<<nodeBlocks, 256, 0, stream>>>(XLR, att1, off, srcPos, b1, Hb);

    // ---- layers 2 & 3 (bf16 Hb, K=512; conv2 applied twice) ----
    for (int rep = 0; rep < 2; ++rep) {
        gemm_mfma_bt<bf16><<<gemmGrid, 256, 0, stream>>>(Hb, W2T, XLR, nullptr, NN, D2, D);
        gat_edge_fused<<<nodeBlocks, 256, 0, stream>>>(XLR, att2, off, srcPos, b2, Hb);
    }

    // ---- classifier: C[NN,49] fp32 = Hb @ Wc + bc (N padded to 128) ----
    dim3 gridc(1, (NN + 127) / 128);
    gemm_mfma_bt<float><<<gridc, 256, 0, stream>>>(Hb, WcT, out, bc, NN, OUTC, D);
}

// Round 7
// 640.790 us; speedup vs baseline: 6.1243x; 1.0290x over previous
//
#include <hip/hip_runtime.h>
#include <hip/hip_bf16.h>

// Problem constants (from reference setup_inputs)
constexpr int NN   = 50000;   // nodes
constexpr int EE   = 400000;  // edges (before self loops)
constexpr int EP   = 450000;  // edges + self loops
constexpr int D    = 512;     // HEADS*CH
constexpr int D2   = 1024;    // XL||XR fused row stride
constexpr int F0   = 55;      // input feature dim
constexpr int F0P  = 64;      // padded to MFMA K granularity
constexpr int OUTC = 49;      // classifier out dim

typedef __hip_bfloat16 bf16;

using frag_ab = __attribute__((ext_vector_type(8))) short;  // 8 bf16 (4 VGPRs)
using frag_cd = __attribute__((ext_vector_type(4))) float;  // 4 fp32

__device__ inline void stf(float* p, float v) { *p = v; }
__device__ inline void stf(bf16* p, float v)  { *p = __float2bfloat16(v); }

// unpack 8 bf16 (packed in a uint4) to 8 floats
__device__ inline void unpack8(uint4 u, float* f) {
    unsigned w[4] = {u.x, u.y, u.z, u.w};
    #pragma unroll
    for (int j = 0; j < 4; ++j) {
        __hip_bfloat162 h = *(__hip_bfloat162*)&w[j];
        float2 t = __bfloat1622float2(h);
        f[2 * j] = t.x; f[2 * j + 1] = t.y;
    }
}

// ---------------------------------------------------------------------------
// MFMA bf16 GEMM (m97 structure): C[M,*] = A[M,K] @ B, with B passed
// TRANSPOSED as Bt[*,K]. 128x128 tile, BK=32, 256 thr, 4 waves x 4x4 frags.
// Ncs = C row stride AND column bound (cols >= Ncs not stored).
// Grid.x*128 must be <= rows of Bt; K % 32 == 0.
// When gridDim.x == 8: XCD-aware swizzle so all 8 column tiles of a row-slab
// run on ONE XCD consecutively -> A slab served from that XCD's L2 (1 fetch).
// ---------------------------------------------------------------------------
template <typename TC>
__global__ __launch_bounds__(256) void gemm_mfma_bt(
    const bf16* __restrict__ A,   // [M,K]
    const bf16* __restrict__ Bt,  // [gridx*128, K]
    TC* __restrict__ C,           // [M, Ncs]
    const float* __restrict__ bias,
    int M, int Ncs, int K)
{
    constexpr int BM = 128, BN = 128, BK = 32;
    __shared__ bf16 As[BM * BK];  // row-major, stride BK (64 B/row)
    __shared__ bf16 Bs[BN * BK];

    int bx = blockIdx.x, by = blockIdx.y;
    if (gridDim.x == 8) {
        // bid%8 selects XCD (round-robin dispatch); keep row-slab on one XCD
        int bid = by * 8 + bx;
        bx = (bid >> 3) & 7;
        by = (bid & 7) + ((bid >> 6) << 3);
        if (by * BM >= M) return;   // uniform across block
    }

    const int tid  = threadIdx.x;
    const int wave = tid >> 6;
    const int lane = tid & 63;
    const int rowBase = by * BM;
    const int colBase = bx * BN;

    frag_cd acc[4][4] = {};

    int arow0 = rowBase + wave * 32 + (lane >> 2);
    int arow1 = arow0 + 16;
    if (arow0 >= M) arow0 = M - 1;   // clamp: garbage rows never stored
    if (arow1 >= M) arow1 = M - 1;
    const bf16* gA0 = A + (size_t)arow0 * K + (lane & 3) * 8;
    const bf16* gA1 = A + (size_t)arow1 * K + (lane & 3) * 8;
    const int brow0 = colBase + wave * 32 + (lane >> 2);
    const bf16* gB0 = Bt + (size_t)brow0 * K + (lane & 3) * 8;
    const bf16* gB1 = gB0 + (size_t)16 * K;

    bf16* lA0 = &As[(wave * 32)      * BK];
    bf16* lA1 = &As[(wave * 32 + 16) * BK];
    bf16* lB0 = &Bs[(wave * 32)      * BK];
    bf16* lB1 = &Bs[(wave * 32 + 16) * BK];

    const int m  = lane & 15;
    const int kq = lane >> 4;
    const int wm = (wave >> 1) * 64;
    const int wn = (wave & 1) * 64;

    for (int k0 = 0; k0 < K; k0 += BK) {
        __builtin_amdgcn_global_load_lds(
            (const __attribute__((address_space(1))) void*)(gA0 + k0),
            (__attribute__((address_space(3))) void*)lA0, 16, 0, 0);
        __builtin_amdgcn_global_load_lds(
            (const __attribute__((address_space(1))) void*)(gA1 + k0),
            (__attribute__((address_space(3))) void*)lA1, 16, 0, 0);
        __builtin_amdgcn_global_load_lds(
            (const __attribute__((address_space(1))) void*)(gB0 + k0),
            (__attribute__((address_space(3))) void*)lB0, 16, 0, 0);
        __builtin_amdgcn_global_load_lds(
            (const __attribute__((address_space(1))) void*)(gB1 + k0),
            (__attribute__((address_space(3))) void*)lB1, 16, 0, 0);
        __syncthreads();

        frag_ab a[4], b[4];
        #pragma unroll
        for (int i = 0; i < 4; ++i)
            a[i] = *(const frag_ab*)&As[(wm + i * 16 + m) * BK + kq * 8];
        #pragma unroll
        for (int j = 0; j < 4; ++j)
            b[j] = *(const frag_ab*)&Bs[(wn + j * 16 + m) * BK + kq * 8];
        #pragma unroll
        for (int i = 0; i < 4; ++i)
            #pragma unroll
            for (int j = 0; j < 4; ++j)
                acc[i][j] = __builtin_amdgcn_mfma_f32_16x16x32_bf16(
                    a[i], b[j], acc[i][j], 0, 0, 0);
        __syncthreads();
    }

    // epilogue: C/D layout col=lane&15, row=(lane>>4)*4+reg  [m89/m91 verified]
    #pragma unroll
    for (int i = 0; i < 4; ++i) {
        #pragma unroll
        for (int r = 0; r < 4; ++r) {
            int row = rowBase + wm + i * 16 + kq * 4 + r;
            if (row >= M) continue;
            #pragma unroll
            for (int j = 0; j < 4; ++j) {
                int col = colBase + wn + j * 16 + m;
                if (col >= Ncs) continue;
                float v = acc[i][j][r];
                if (bias) v += bias[col];
                stf(&C[(size_t)row * Ncs + col], v);
            }
        }
    }
}

// ---------------------------------------------------------------------------
// weight prep kernels
// ---------------------------------------------------------------------------
// fp32 W[K,N] -> bf16 Wt[N,K], 32x32 LDS tile (for 512x512 weights)
__global__ void convert_transpose(const float* __restrict__ W, bf16* __restrict__ Wt,
                                  int K, int N) {
    __shared__ float tile[32][33];
    int bn = blockIdx.x * 32, bk = blockIdx.y * 32;
    int tx = threadIdx.x & 31, ty = threadIdx.x >> 5;  // 32x8
    #pragma unroll
    for (int i = 0; i < 32; i += 8)
        tile[ty + i][tx] = W[(size_t)(bk + ty + i) * N + bn + tx];
    __syncthreads();
    #pragma unroll
    for (int i = 0; i < 32; i += 8)
        Wt[(size_t)(bn + ty + i) * K + bk + tx] = __float2bfloat16(tile[tx][ty + i]);
}

// x[NN,55] fp32 -> Xpad[NN,64] bf16 (zero pad)
__global__ void pad_convert_x(const float* __restrict__ x, bf16* __restrict__ Xp) {
    int idx = blockIdx.x * blockDim.x + threadIdx.x;
    if (idx >= NN * F0P) return;
    int n = idx >> 6, t = idx & 63;
    float v = (t < F0) ? x[n * F0 + t] : 0.f;
    Xp[idx] = __float2bfloat16(v);
}

// W1[55,512] fp32 -> W1t[512,64] bf16 (zero pad K)
__global__ void conv_transpose_w1(const float* __restrict__ W, bf16* __restrict__ Wt) {
    int n = blockIdx.x;           // 512
    int k = threadIdx.x;          // 64
    float v = (k < F0) ? W[(size_t)k * D + n] : 0.f;
    Wt[n * F0P + k] = __float2bfloat16(v);
}

// Wc[512,49] fp32 -> WcT[128,512] bf16 (rows >= 49 zero)
__global__ void conv_transpose_wc(const float* __restrict__ W, bf16* __restrict__ Wt) {
    int n = blockIdx.x;           // 128
    for (int k = threadIdx.x; k < D; k += blockDim.x) {
        float v = (n < OUTC) ? W[(size_t)k * OUTC + n] : 0.f;
        Wt[(size_t)n * D + k] = __float2bfloat16(v);
    }
}

// ---------------------------------------------------------------------------
__global__ void zero_ints(int* __restrict__ p, int n) {
    int i = blockIdx.x * blockDim.x + threadIdx.x;
    if (i < n) p[i] = 0;
}

// ---------------------------------------------------------------------------
// CSR build by destination; srcPos[pos] = source node of CSR slot pos
// ---------------------------------------------------------------------------
__global__ void count_dst(const int* __restrict__ dstIdx, int* __restrict__ cnt) {
    int e = blockIdx.x * blockDim.x + threadIdx.x;
    if (e >= EP) return;
    int dst = (e < EE) ? dstIdx[e] : (e - EE);
    atomicAdd(&cnt[dst], 1);
}

// --- 3-phase parallel exclusive scan over cnt[NN] -> off[NN+1] -------------
__global__ void scan_blocks(const int* __restrict__ cnt, int* __restrict__ off,
                            int* __restrict__ bsum) {
    __shared__ int sh[1024];
    int i = blockIdx.x * 1024 + threadIdx.x;
    int v = (i < NN) ? cnt[i] : 0;
    sh[threadIdx.x] = v;
    __syncthreads();
    #pragma unroll
    for (int d = 1; d < 1024; d <<= 1) {
        int t = (threadIdx.x >= d) ? sh[threadIdx.x - d] : 0;
        __syncthreads();
        sh[threadIdx.x] += t;
        __syncthreads();
    }
    if (i < NN) off[i] = sh[threadIdx.x] - v;   // local exclusive
    if (threadIdx.x == 1023) bsum[blockIdx.x] = sh[1023];
}

__global__ void scan_bsums(int* __restrict__ bsum, int* __restrict__ bbase,
                           int* __restrict__ off, int nb) {
    int lane = threadIdx.x;  // single wave of 64
    int orig = (lane < nb) ? bsum[lane] : 0;
    int v = orig;
    #pragma unroll
    for (int d = 1; d < 64; d <<= 1) {
        int t = __shfl_up(v, d);
        if (lane >= d) v += t;
    }
    if (lane < nb) bbase[lane] = v - orig;      // exclusive base per block
    if (lane == 63) off[NN] = v;                // grand total
}

__global__ void add_base(int* __restrict__ off, const int* __restrict__ bbase) {
    int i = blockIdx.x * 1024 + threadIdx.x;
    if (blockIdx.x == 0 || i >= NN) return;
    off[i] += bbase[blockIdx.x];
}

__global__ void fill_srcpos(const int* __restrict__ srcIdx, const int* __restrict__ dstIdx,
                            const int* __restrict__ off, int* __restrict__ cnt,
                            int* __restrict__ srcPos) {
    int e = blockIdx.x * blockDim.x + threadIdx.x;
    if (e >= EP) return;
    int dst = (e < EE) ? dstIdx[e] : (e - EE);
    int src = (e < EE) ? srcIdx[e] : (e - EE);
    int pos = off[dst] + atomicAdd(&cnt[dst], 1);
    srcPos[pos] = src;
}

// ---------------------------------------------------------------------------
// FUSED per-node GATv2 edge phase (flash-style online softmax + aggregate).
// One wave per destination node. Lane l owns channels [l*8, l*8+8); head = l>>4.
// XLR row layout: [XL(512) | XR(512)], stride D2. Output Hb[NN,D] + bias + ELU.
// Gather is software-pipelined 2 deep (uint4 regs) to hide L2/LLC latency.
// ---------------------------------------------------------------------------
__global__ __launch_bounds__(256) void gat_edge_fused(
    const bf16* __restrict__ XLR, const float* __restrict__ att,
    const int* __restrict__ off, const int* __restrict__ srcPos,
    const float* __restrict__ bias, bf16* __restrict__ Hout)
{
    int v = blockIdx.x * 4 + (threadIdx.x >> 6);
    if (v >= NN) return;
    int lane = threadIdx.x & 63;

    uint4 ru = *(const uint4*)(XLR + (size_t)v * D2 + D + lane * 8);
    float xr[8]; unpack8(ru, xr);
    const float4* a4 = (const float4*)(att + lane * 8);
    float4 aa = a4[0], ab = a4[1];
    float at[8] = {aa.x, aa.y, aa.z, aa.w, ab.x, ab.y, ab.z, ab.w};

    int s0 = off[v], s1 = off[v + 1];
    float m = -1e30f, den = 0.f;
    float acc[8] = {};

    uint4 lb0 = {0, 0, 0, 0}, lb1 = {0, 0, 0, 0};
    if (s0 < s1)     lb0 = *(const uint4*)(XLR + (size_t)srcPos[s0] * D2 + lane * 8);
    if (s0 + 1 < s1) lb1 = *(const uint4*)(XLR + (size_t)srcPos[s0 + 1] * D2 + lane * 8);

    for (int i = s0; i < s1; ++i) {
        uint4 cur = lb0;
        lb0 = lb1;
        if (i + 2 < s1)
            lb1 = *(const uint4*)(XLR + (size_t)srcPos[i + 2] * D2 + lane * 8);

        float xl[8]; unpack8(cur, xl);
        float s = 0.f;
        #pragma unroll
        for (int j = 0; j < 8; ++j) {
            float t = xl[j] + xr[j];
            t = t > 0.f ? t : 0.2f * t;    // LeakyReLU(0.2)
            s += t * at[j];
        }
        s += __shfl_xor(s, 1);
        s += __shfl_xor(s, 2);
        s += __shfl_xor(s, 4);
        s += __shfl_xor(s, 8);             // all 16 lanes of head hold logit
        float mn = fmaxf(m, s);
        float scale = __expf(m - mn);      // first iter: exp(-inf) = 0
        float p = __expf(s - mn);
        den = den * scale + p;
        #pragma unroll
        for (int j = 0; j < 8; ++j) acc[j] = acc[j] * scale + p * xl[j];
        m = mn;
    }
    float r = 1.f / den;

    const float4* b4 = (const float4*)(bias + lane * 8);
    float4 ba = b4[0], bb = b4[1];
    float bi[8] = {ba.x, ba.y, ba.z, ba.w, bb.x, bb.y, bb.z, bb.w};
    uint4 ou;
    unsigned* ow = (unsigned*)&ou;
    #pragma unroll
    for (int j = 0; j < 4; ++j) {
        float o0 = acc[2 * j] * r + bi[2 * j];
        float o1 = acc[2 * j + 1] * r + bi[2 * j + 1];
        o0 = o0 > 0.f ? o0 : (__expf(o0) - 1.f);   // ELU
        o1 = o1 > 0.f ? o1 : (__expf(o1) - 1.f);
        __hip_bfloat162 h{__float2bfloat16(o0), __float2bfloat16(o1)};
        ow[j] = *(unsigned*)&h;
    }
    *(uint4*)(Hout + (size_t)v * D + lane * 8) = ou;
}

// ---------------------------------------------------------------------------
extern "C" void kernel_launch(void* const* d_in, const int* in_sizes, int n_in,
                              void* d_out, int out_size, void* d_ws, size_t ws_size,
                              hipStream_t stream) {
    const float* x    = (const float*)d_in[0];
    const int*   ei   = (const int*)d_in[1];
    const float* W1l  = (const float*)d_in[2];
    const float* W1r  = (const float*)d_in[3];
    const float* att1 = (const float*)d_in[4];
    const float* b1   = (const float*)d_in[5];
    const float* W2l  = (const float*)d_in[6];
    const float* W2r  = (const float*)d_in[7];
    const float* att2 = (const float*)d_in[8];
    const float* b2   = (const float*)d_in[9];
    const float* Wc   = (const float*)d_in[10];
    const float* bc   = (const float*)d_in[11];
    float* out = (float*)d_out;

    const int* srcIdx = ei;
    const int* dstIdx = ei + EE;

    constexpr int NB = (NN + 1023) / 1024;   // 49 scan blocks

    // workspace carve — total ≈ 166 MB
    bf16* XLR  = (bf16*)d_ws;                    // NN*D2   (XL || XR)
    bf16* Hb   = XLR + (size_t)NN * D2;          // NN*D
    bf16* Xpad = Hb + (size_t)NN * D;            // NN*F0P
    bf16* W2T  = Xpad + (size_t)NN * F0P;        // 1024*D   (W2lT || W2rT rows)
    bf16* W1T  = W2T + (size_t)D2 * D;           // 1024*F0P
    bf16* WcT  = W1T + (size_t)D2 * F0P;         // 128*D
    int* cnt   = (int*)(WcT + (size_t)128 * D);  // NN
    int* cnt2  = cnt + NN;                       // NN
    int* off   = cnt2 + NN;                      // NN+1
    int* srcPos= off + (NN + 1);                 // EP
    int* bsum  = srcPos + EP;                    // NB
    int* bbase = bsum + NB;                      // NB

    // ---- one-time per call: CSR build + weight prep ----
    zero_ints<<<(2 * NN + 255) / 256, 256, 0, stream>>>(cnt, 2 * NN);
    count_dst<<<(EP + 255) / 256, 256, 0, stream>>>(dstIdx, cnt);
    scan_blocks<<<NB, 1024, 0, stream>>>(cnt, off, bsum);
    scan_bsums<<<1, 64, 0, stream>>>(bsum, bbase, off, NB);
    add_base<<<NB, 1024, 0, stream>>>(off, bbase);
    fill_srcpos<<<(EP + 255) / 256, 256, 0, stream>>>(srcIdx, dstIdx, off, cnt2, srcPos);

    dim3 ctGrid(D / 32, D / 32);
    convert_transpose<<<ctGrid, 256, 0, stream>>>(W2l, W2T, D, D);                 // rows 0..511
    convert_transpose<<<ctGrid, 256, 0, stream>>>(W2r, W2T + (size_t)D * D, D, D); // rows 512..1023
    conv_transpose_w1<<<D, F0P, 0, stream>>>(W1l, W1T);
    conv_transpose_w1<<<D, F0P, 0, stream>>>(W1r, W1T + (size_t)D * F0P);
    conv_transpose_wc<<<128, 256, 0, stream>>>(Wc, WcT);
    pad_convert_x<<<(NN * F0P + 255) / 256, 256, 0, stream>>>(x, Xpad);

    // fused L+R GEMM: N=1024, grid.y padded so the XCD swizzle covers all slabs
    dim3 gemmGrid(D2 / 128, ((NN + 127) / 128 + 7) / 8 * 8 + 8);  // 8 x 392
    int nodeBlocks = (NN + 3) / 4;

    // ---- layer 1 (Xpad bf16, K=64): one GEMM produces XL||XR ----
    gemm_mfma_bt<bf16><<<gemmGrid, 256, 0, stream>>>(Xpad, W1T, XLR, nullptr, NN, D2, F0P);
    gat_edge_fused<<<nodeBlocks, 256, 0, stream>>>(XLR, att1, off, srcPos, b1, Hb);

    // ---- layers 2 & 3 (bf16 Hb, K=512; conv2 applied twice) ----
    for (int rep = 0; rep < 2; ++rep) {
        gemm_mfma_bt<bf16><<<gemmGrid, 256, 0, stream>>>(Hb, W2T, XLR, nullptr, NN, D2, D);
        gat_edge_fused<<<nodeBlocks, 256, 0, stream>>>(XLR, att2, off, srcPos, b2, Hb);
    }

    // ---- classifier: C[NN,49] fp32 = Hb @ Wc + bc (N padded to 128) ----
    dim3 gridc(1, (NN + 127) / 128);
    gemm_mfma_bt<float><<<gridc, 256, 0, stream>>>(Hb, WcT, out, bc, NN, OUTC, D);
}